// Round 9
// baseline (135.817 us; speedup 1.0000x reference)
//
#include <hip/hip_runtime.h>
#include <math.h>

#define BB 4
#define SQL 512
#define SKL 512
#define HH 256
#define AA 128

// 2 * log2(e): Qt/Kt pre-scaled so the score loop feeds v_exp_f32 (2^x) directly.
#define PRESCALE 2.8853900817779268f

__device__ inline void fma4(float4& a, float s, const float4& b) {
    a.x = fmaf(s, b.x, a.x); a.y = fmaf(s, b.y, a.y);
    a.z = fmaf(s, b.z, a.z); a.w = fmaf(s, b.w, a.w);
}

__device__ inline unsigned short f_to_bf16(float f) {   // round-to-nearest-even
    unsigned u = __float_as_uint(f);
    return (unsigned short)((u + 0x7fffu + ((u >> 16) & 1u)) >> 16);
}
__device__ inline float4 bf16x4_to_f4(uint2 u) {
    float4 r;
    r.x = __uint_as_float(u.x << 16);
    r.y = __uint_as_float(u.x & 0xffff0000u);
    r.z = __uint_as_float(u.y << 16);
    r.w = __uint_as_float(u.y & 0xffff0000u);
    return r;
}

// ---------------------------------------------------------------------------
// Kernel 1 "prep": Qt = PRESCALE*(Q@W_q), Kt = PRESCALE*(K@W_k), VW = bf16(V@W_o).
// grid 512 x 256 thr (2 blocks/CU -> 2 waves/SIMD, vs R8's 1 wave/SIMD).
// Block = 16 rows x 128 cols; thread = 2 rows x 4 cols.
//   [0,128): Qt   [128,256): Kt   [256,512): VW (row-tile, col-half)
// K-loop in 8-k groups, register double-buffered on BOTH operands:
// 8 global b128 W-loads + 8 LDS b64 row-loads stay in flight one full group
// (~128 issue cycles x 2 waves) ahead -> L2 latency covered.
// ---------------------------------------------------------------------------
__global__ __launch_bounds__(256) void prep_kernel(
    const float* __restrict__ Q, const float* __restrict__ K,
    const float* __restrict__ V,
    const float* __restrict__ Wq, const float* __restrict__ Wk,
    const float* __restrict__ Wo,
    float* __restrict__ Qt, float* __restrict__ Kt,
    unsigned short* __restrict__ VW)
{
    __shared__ float rowsT[256 * 18 + 2];   // 18 KB, rowsT[h*18 + r], r in [0,16)
    int tid = threadIdx.x;
    int bid = blockIdx.x;

    const float* X; const float* W;
    int ldW, col0, r0, kind;
    if (bid < 128)      { X=Q; W=Wq; ldW=AA; kind=0; r0=bid*16;        col0=0; }
    else if (bid < 256) { X=K; W=Wk; ldW=AA; kind=1; r0=(bid-128)*16;  col0=0; }
    else { int b2=bid-256; X=V; W=Wo; ldW=HH; kind=2; r0=(b2>>1)*16; col0=(b2&1)*128; }

    int mg = tid >> 5;            // 0..7 -> rows 2mg, 2mg+1
    int n4 = tid & 31;            // float4 col
    int rpair = mg << 1;
    const float* Wg = W + col0 + (n4 << 2);

    // prefetch W group 0 (8 k) while rows stage
    float4 wA[8], wB[8];
    #pragma unroll
    for (int j = 0; j < 8; ++j)
        wA[j] = *(const float4*)(Wg + (size_t)j * ldW);

    // stage 16 input rows (4096 floats) transposed: rowsT[h][r]
    {
        const float4* Xv = (const float4*)(X + (size_t)r0 * HH);
        #pragma unroll
        for (int it = 0; it < 4; ++it) {
            int l = tid + it * 256;          // 1024 float4
            int r = l >> 6, h4 = (l & 63) << 2;
            float4 x = Xv[l];
            rowsT[(h4 + 0) * 18 + r] = x.x;
            rowsT[(h4 + 1) * 18 + r] = x.y;
            rowsT[(h4 + 2) * 18 + r] = x.z;
            rowsT[(h4 + 3) * 18 + r] = x.w;
        }
    }
    __syncthreads();

    float2 aA[8], aB[8];
    #pragma unroll
    for (int j = 0; j < 8; ++j)
        aA[j] = *(const float2*)&rowsT[j * 18 + rpair];

    float4 accA = {0,0,0,0}, accB = {0,0,0,0};

    for (int g = 0; g < 32; g += 2) {
        {   // prefetch group g+1 into B
            const float* Wb = Wg + (size_t)((g + 1) * 8) * ldW;
            int hb = (g + 1) * 8;
            #pragma unroll
            for (int j = 0; j < 8; ++j) {
                wB[j] = *(const float4*)(Wb + (size_t)j * ldW);
                aB[j] = *(const float2*)&rowsT[(hb + j) * 18 + rpair];
            }
        }
        #pragma unroll
        for (int j = 0; j < 8; ++j) {        // compute group g from A
            fma4(accA, aA[j].x, wA[j]);
            fma4(accB, aA[j].y, wA[j]);
        }
        if (g + 2 < 32) {                    // prefetch group g+2 into A
            const float* Wb = Wg + (size_t)((g + 2) * 8) * ldW;
            int hb = (g + 2) * 8;
            #pragma unroll
            for (int j = 0; j < 8; ++j) {
                wA[j] = *(const float4*)(Wb + (size_t)j * ldW);
                aA[j] = *(const float2*)&rowsT[(hb + j) * 18 + rpair];
            }
        }
        #pragma unroll
        for (int j = 0; j < 8; ++j) {        // compute group g+1 from B
            fma4(accA, aB[j].x, wB[j]);
            fma4(accB, aB[j].y, wB[j]);
        }
    }

    if (kind < 2) {
        float* Y = (kind == 0) ? Qt : Kt;
        accA.x *= PRESCALE; accA.y *= PRESCALE; accA.z *= PRESCALE; accA.w *= PRESCALE;
        accB.x *= PRESCALE; accB.y *= PRESCALE; accB.z *= PRESCALE; accB.w *= PRESCALE;
        *(float4*)(Y + (size_t)(r0 + rpair)     * AA + (n4 << 2)) = accA;
        *(float4*)(Y + (size_t)(r0 + rpair + 1) * AA + (n4 << 2)) = accB;
    } else {
        ushort4 sa = { f_to_bf16(accA.x), f_to_bf16(accA.y),
                       f_to_bf16(accA.z), f_to_bf16(accA.w) };
        ushort4 sb = { f_to_bf16(accB.x), f_to_bf16(accB.y),
                       f_to_bf16(accB.z), f_to_bf16(accB.w) };
        *(ushort4*)(VW + (size_t)(r0 + rpair)     * HH + col0 + (n4 << 2)) = sa;
        *(ushort4*)(VW + (size_t)(r0 + rpair + 1) * HH + col0 + (n4 << 2)) = sb;
    }
}

// ---------------------------------------------------------------------------
// Kernel 2 "score_part" (unchanged from R8): raw scores, (batch, q-pair, k-half).
// grid = 2048 blocks x 256 thr (8 blocks/CU). ag = tid&7 owns 16 a's.
// ---------------------------------------------------------------------------
__global__ __launch_bounds__(256) void score_part(
    const float* __restrict__ Qt, const float* __restrict__ Kt,
    const float* __restrict__ v,  float* __restrict__ scores)
{
    __shared__ float sc[2][256];         // 2 KB

    int tid = threadIdx.x;
    int bid = blockIdx.x;
    int b    = bid >> 9;                 // 512 blocks per batch
    int rem  = bid & 511;
    int q0   = rem & ~1;                 // q-pair base
    int half = rem & 1;                  // k-half
    int ag = tid & 7;                    // a-range [16ag, 16ag+16)
    int kl = tid >> 3;                   // k within 32-chunk

    float q0r[16], dr[16], v2[16];
    {
        const float4* vp  = (const float4*)(v + ag * 16);
        const float4* qp0 = (const float4*)(Qt + (size_t)(b * SQL + q0)     * AA + ag * 16);
        const float4* qp1 = (const float4*)(Qt + (size_t)(b * SQL + q0 + 1) * AA + ag * 16);
        #pragma unroll
        for (int j4 = 0; j4 < 4; ++j4) {
            float4 vv4 = vp[j4];
            float4 a0  = qp0[j4];
            float4 a1  = qp1[j4];
            *(float4*)&q0r[j4 * 4] = a0;
            dr[j4*4+0] = __builtin_amdgcn_exp2f(a1.x - a0.x);
            dr[j4*4+1] = __builtin_amdgcn_exp2f(a1.y - a0.y);
            dr[j4*4+2] = __builtin_amdgcn_exp2f(a1.z - a0.z);
            dr[j4*4+3] = __builtin_amdgcn_exp2f(a1.w - a0.w);
            v2[j4*4+0] = 2.0f * vv4.x;
            v2[j4*4+1] = 2.0f * vv4.y;
            v2[j4*4+2] = 2.0f * vv4.z;
            v2[j4*4+3] = 2.0f * vv4.w;
        }
    }

    float S_all;
    {
        float ls = 0.f;
        #pragma unroll
        for (int j = 0; j < 16; ++j) ls += v2[j];
        ls += __shfl_xor(ls, 1);
        ls += __shfl_xor(ls, 2);
        ls += __shfl_xor(ls, 4);
        S_all = 0.5f * ls;
    }

    const float4* kp = (const float4*)(Kt + (size_t)(b * SKL + half * 256 + kl) * AA + ag * 16);
    float4 n0 = kp[0], n1 = kp[1], n2 = kp[2], n3 = kp[3];
    for (int c = 0; c < 8; ++c) {
        float kt[16];
        *(float4*)&kt[0]  = n0;
        *(float4*)&kt[4]  = n1;
        *(float4*)&kt[8]  = n2;
        *(float4*)&kt[12] = n3;
        if (c < 7) {
            const float4* np = kp + (size_t)(c + 1) * 32 * (AA / 4);
            n0 = np[0]; n1 = np[1]; n2 = np[2]; n3 = np[3];
        }

        float p0 = 0.f, p1 = 0.f;
        #pragma unroll
        for (int j = 0; j < 16; ++j) {
            float x0 = q0r[j] + kt[j];
            float e0 = __builtin_amdgcn_exp2f(x0);
            float e1 = e0 * dr[j];                  // = 2^(q1+kv)
            float r0 = __builtin_amdgcn_rcpf(e0 + 1.0f);
            float r1 = __builtin_amdgcn_rcpf(e1 + 1.0f);
            p0 = fmaf(v2[j], r0, p0);
            p1 = fmaf(v2[j], r1, p1);
        }
        p0 += __shfl_xor(p0, 1); p1 += __shfl_xor(p1, 1);
        p0 += __shfl_xor(p0, 2); p1 += __shfl_xor(p1, 2);
        p0 += __shfl_xor(p0, 4); p1 += __shfl_xor(p1, 4);
        if (ag == 0) {
            sc[0][c * 32 + kl] = S_all - p0;
            sc[1][c * 32 + kl] = S_all - p1;
        }
    }
    __syncthreads();

    if (tid < 128) {    // vectored store of the 2x256 raw scores
        int q = tid >> 6, i = tid & 63;
        float4 val = *(float4*)&sc[q][i << 2];
        *(float4*)(scores + (size_t)(b * SQL + q0 + q) * SKL + half * 256 + (i << 2)) = val;
    }
}

// ---------------------------------------------------------------------------
// Kernel 3 "softepi": softmax in place + out = weights@VW + b_o.
// grid = 1024 blocks x 256 thr (4 blocks/CU -> 4 waves/SIMD; R8 ran 2 blocks/CU).
// Block = (batch, 2 q-rows). Softmax: 4 waves = (row) x (half) with LDS combine.
// Epilogue: wave w owns k-quarter for BOTH q-rows; bf16 VW; LDS tree-reduce.
// ---------------------------------------------------------------------------
__global__ __launch_bounds__(256) void softepi_kernel(
    const unsigned short* __restrict__ VW, const float* __restrict__ bo,
    float* __restrict__ weights, float* __restrict__ out)
{
    __shared__ float sw[2][SKL];         // 4 KB
    __shared__ float pout[4][2][HH];     // 8 KB
    __shared__ float pm[2][2], ps[2][2];

    int tid = threadIdx.x;
    int b  = blockIdx.x >> 8;
    int q0 = (blockIdx.x & 255) << 1;
    int wave = tid >> 6, lane = tid & 63;
    int qi = wave & 1, half = wave >> 1;

    // softmax: 4 waves = (row) x (half)
    {
        float* wrow = weights + (size_t)(b * SQL + q0 + qi) * SKL + half * 256;
        float4 sv = *(float4*)(wrow + (lane << 2));
        float m = fmaxf(fmaxf(sv.x, sv.y), fmaxf(sv.z, sv.w));
        #pragma unroll
        for (int off = 32; off; off >>= 1) m = fmaxf(m, __shfl_xor(m, off));
        if (lane == 0) pm[qi][half] = m;
        __syncthreads();
        float M = fmaxf(pm[qi][0], pm[qi][1]);
        float4 e;
        e.x = __builtin_amdgcn_exp2f((sv.x - M) * 1.44269504f);
        e.y = __builtin_amdgcn_exp2f((sv.y - M) * 1.44269504f);
        e.z = __builtin_amdgcn_exp2f((sv.z - M) * 1.44269504f);
        e.w = __builtin_amdgcn_exp2f((sv.w - M) * 1.44269504f);
        float s = (e.x + e.y) + (e.z + e.w);
        #pragma unroll
        for (int off = 32; off; off >>= 1) s += __shfl_xor(s, off);
        if (lane == 0) ps[qi][half] = s;
        __syncthreads();
        float rinv = 1.0f / (ps[qi][0] + ps[qi][1]);
        float4 w4 = { e.x * rinv, e.y * rinv, e.z * rinv, e.w * rinv };
        *(float4*)&sw[qi][half * 256 + (lane << 2)] = w4;
        *(float4*)(wrow + (lane << 2)) = w4;
    }
    __syncthreads();

    // epilogue: wave w owns k in [128w, 128w+128); VW bf16
    {
        const uint2* VWb = (const uint2*)(VW + (size_t)b * SKL * HH);
        float4 a0 = {0,0,0,0}, a1 = {0,0,0,0};
        int kbase = wave * 128;
        for (int k4 = 0; k4 < 32; ++k4) {
            int kk = kbase + k4 * 4;
            float4 w0 = *(const float4*)&sw[0][kk];   // wave-uniform b128
            float4 w1 = *(const float4*)&sw[1][kk];
            uint2 u0 = VWb[(size_t)(kk + 0) * (HH / 4) + lane];
            uint2 u1 = VWb[(size_t)(kk + 1) * (HH / 4) + lane];
            uint2 u2 = VWb[(size_t)(kk + 2) * (HH / 4) + lane];
            uint2 u3 = VWb[(size_t)(kk + 3) * (HH / 4) + lane];
            float4 v0 = bf16x4_to_f4(u0);
            float4 v1 = bf16x4_to_f4(u1);
            float4 v2 = bf16x4_to_f4(u2);
            float4 v3 = bf16x4_to_f4(u3);
            fma4(a0, w0.x, v0); fma4(a1, w1.x, v0);
            fma4(a0, w0.y, v1); fma4(a1, w1.y, v1);
            fma4(a0, w0.z, v2); fma4(a1, w1.z, v2);
            fma4(a0, w0.w, v3); fma4(a1, w1.w, v3);
        }
        *(float4*)&pout[wave][0][lane << 2] = a0;
        *(float4*)&pout[wave][1][lane << 2] = a1;
    }
    __syncthreads();
    {
        int h = tid;
        float bias = bo[h];
        #pragma unroll
        for (int q2 = 0; q2 < 2; ++q2) {
            float s = bias + pout[0][q2][h] + pout[1][q2][h]
                           + pout[2][q2][h] + pout[3][q2][h];
            out[(size_t)(b * SQL + q0 + q2) * HH + h] = s;
        }
    }
}

// ---------------------------------------------------------------------------
extern "C" void kernel_launch(void* const* d_in, const int* in_sizes, int n_in,
                              void* d_out, int out_size, void* d_ws, size_t ws_size,
                              hipStream_t stream)
{
    const float* Q  = (const float*)d_in[0];
    const float* K  = (const float*)d_in[1];
    const float* V  = (const float*)d_in[2];
    const float* Wq = (const float*)d_in[3];
    const float* Wk = (const float*)d_in[4];
    const float* v  = (const float*)d_in[5];
    const float* Wo = (const float*)d_in[6];
    const float* bo = (const float*)d_in[7];

    float* out     = (float*)d_out;                   // (B,SQ,H) = 524288
    float* weights = out + (size_t)BB * SQL * HH;     // (B,SQ,SK) = 1048576

    float* Qt = (float*)d_ws;                         // 262144 floats
    float* Kt = Qt + (size_t)BB * SQL * AA;           // 262144 floats
    unsigned short* VW = (unsigned short*)(Kt + (size_t)BB * SKL * AA); // 524288 bf16

    prep_kernel   <<<512, 256, 0, stream>>>(Q, K, V, Wq, Wk, Wo, Qt, Kt, VW);
    score_part    <<<2048, 256, 0, stream>>>(Qt, Kt, v, weights);
    softepi_kernel<<<1024, 256, 0, stream>>>(VW, bo, weights, out);
}